// Round 2
// baseline (288.839 us; speedup 1.0000x reference)
//
#include <hip/hip_runtime.h>
#include <hip/hip_bf16.h>

// CQAttention: B=16, Lc=1024, Lq=512, d=512.  f32 I/O, bf16 MFMA GEMMs, f32 acc.
// Round 10: k_mfma_out rebuilt as a PURE 4-segment gload_lds GEMM
// ([Cbf|Aw|CAw|CBw] @ OW^T, K=2048, BK=64, 32 KiB LDS) — the on-the-fly
// bf16 assembly is gone.  CA is emitted by k_mfma_A's epilogue (f32 acc x
// f32 C), CB by k_mfma_Bm's epilogue; Cbf/OWbf by one late cvt kernel.
// Workspace re-choreographed (all steps <= 72 MiB, verified lifetime map).

#define NB 16
#define LC 1024
#define LQ 512
#define DM 512
#define D4 2048
#define NEGINF (-1e30f)

typedef __bf16 v8bf __attribute__((ext_vector_type(8)));
typedef __bf16 v4bf __attribute__((ext_vector_type(4)));
typedef float  v4f  __attribute__((ext_vector_type(4)));

#define MFMA16 __builtin_amdgcn_mfma_f32_16x16x32_bf16

// direct global->LDS async copy, 16B per lane; LDS dest is wave-uniform base.
#define GLOAD16(gp, lp) __builtin_amdgcn_global_load_lds( \
    (const __attribute__((address_space(1))) void*)(gp), \
    (__attribute__((address_space(3))) void*)(lp), 16, 0, 0)

// ---- 4-wave gload_lds GEMM core: 128x128 tile, wave-tile 64x64, BK=64 ----
#define GEMM_PROLOG \
  __shared__ __bf16 Al[128 * 64], Bl[128 * 64]; \
  int bx = blockIdx.x, by = blockIdx.y, bz = blockIdx.z; \
  xcd_remap(bx, by, bz); \
  const int b = bz, i0 = by * 128, n0 = bx * 128; \
  const int t = threadIdx.x, lane = t & 63, wave = t >> 6; \
  const int wm = wave >> 1, wn = wave & 1, quad = lane >> 4, col = lane & 15; \
  const int srow = wave * 32 + (lane >> 3), scol = (lane & 7) * 8; \
  v4f acc[4][4]; \
  _Pragma("unroll") for (int x = 0; x < 4; ++x) \
  _Pragma("unroll") for (int y = 0; y < 4; ++y) \
  _Pragma("unroll") for (int r = 0; r < 4; ++r) acc[x][y][r] = 0.f;

#define GEMM_KLOOP(Arow, Brow, LDGA, LDGB, KEXT) \
  for (int k0 = 0; k0 < (KEXT); k0 += 64) { \
    _Pragma("unroll") for (int u = 0; u < 4; ++u) { \
      GLOAD16(Arow + (size_t)(u * 8) * (LDGA) + k0, &Al[(wave * 32 + u * 8) * 64]); \
      GLOAD16(Brow + (size_t)(u * 8) * (LDGB) + k0, &Bl[(wave * 32 + u * 8) * 64]); \
    } \
    __syncthreads(); \
    _Pragma("unroll") for (int ko = 0; ko < 2; ++ko) { \
      v8bf af_[4], bf_[4]; \
      _Pragma("unroll") for (int x = 0; x < 4; ++x) \
        af_[x] = *(const v8bf*)&Al[(wm * 64 + x * 16 + col) * 64 + ko * 32 + quad * 8]; \
      _Pragma("unroll") for (int y = 0; y < 4; ++y) \
        bf_[y] = *(const v8bf*)&Bl[(wn * 64 + y * 16 + col) * 64 + ko * 32 + quad * 8]; \
      _Pragma("unroll") for (int x = 0; x < 4; ++x) \
      _Pragma("unroll") for (int y = 0; y < 4; ++y) \
        acc[x][y] = MFMA16(af_[x], bf_[y], acc[x][y], 0, 0, 0); \
    } \
    __syncthreads(); \
  }

// XCD-aware remap (L2 locality for n-tile siblings sharing an A-tile).
__device__ __forceinline__ void xcd_remap(int& bx, int& by, int& bz) {
  const int gx = gridDim.x, gy = gridDim.y, gz = gridDim.z;
  int flat = bx + gx * (by + gy * bz);
  int per = (gx * gy * gz) >> 3;
  int nw = (flat & 7) * per + (flat >> 3);
  bx = nw % gx;
  int r = nw / gx;
  by = r % gy;
  bz = r / gy;
}

// -------- K1: cw1[b,i] = C.w1, qw2[b,j] = Q.w2; also emits Cbf_e = bf16(C)
// -------- and Qw3 = bf16(Q*w3) for the pure-bf16 k_mfma_S. ----
__global__ void k_rowdots(const float* __restrict__ C, const float* __restrict__ Q,
                          const float* __restrict__ w,
                          float* __restrict__ cw1, float* __restrict__ qw2,
                          __bf16* __restrict__ Cbf, __bf16* __restrict__ Qw3) {
  const int wid = threadIdx.x >> 6, lane = threadIdx.x & 63;
  const int row = blockIdx.x * 4 + wid;
  const bool isC = row < NB * LC;
  const int lr = isC ? row : row - NB * LC;
  const float* src = (isC ? C : Q) + (size_t)lr * DM;
  const float* wv  = isC ? w : (w + DM);
  const float* w3  = w + 2 * DM;
  __bf16* dst = (isC ? Cbf : Qw3) + (size_t)lr * DM;
  float v = 0.f;
#pragma unroll
  for (int s = 0; s < 2; ++s) {
    const int k = lane * 4 + s * 256;
    float4 f = *(const float4*)(src + k);
    float4 g = *(const float4*)(wv + k);
    v += f.x * g.x + f.y * g.y + f.z * g.z + f.w * g.w;
    v4bf h;
    if (isC) {
      h[0] = (__bf16)f.x; h[1] = (__bf16)f.y; h[2] = (__bf16)f.z; h[3] = (__bf16)f.w;
    } else {
      float4 s3 = *(const float4*)(w3 + k);
      h[0] = (__bf16)(f.x * s3.x); h[1] = (__bf16)(f.y * s3.y);
      h[2] = (__bf16)(f.z * s3.z); h[3] = (__bf16)(f.w * s3.w);
    }
    *(v4bf*)(dst + k) = h;
  }
#pragma unroll
  for (int off = 32; off; off >>= 1) v += __shfl_down(v, off, 64);
  if (lane == 0) {
    if (isC) cw1[row] = v;
    else     qw2[lr] = v;
  }
}

// ------- batched transpose: f32 in[R][Cd] -> bf16 outT[Cd][R] -------
__global__ void k_transpose(const float* __restrict__ in, __bf16* __restrict__ outT,
                            int R, int Cd) {
  __shared__ __bf16 tile[64][66];
  const int b = blockIdx.z;
  const int r0 = blockIdx.y * 64, c0 = blockIdx.x * 64;
  const int tr = threadIdx.x >> 6, tc = threadIdx.x & 63;
  const float* inb = in + (size_t)b * R * Cd;
  __bf16* outb = outT + (size_t)b * Cd * R;
  for (int r = tr; r < 64; r += 4)
    tile[r][tc] = (__bf16)inb[(size_t)(r0 + r) * Cd + c0 + tc];
  __syncthreads();
  for (int c = tr; c < 64; c += 4)
    outb[(size_t)(c0 + c) * R + r0 + tc] = tile[tc][c];
}

// ------- late cvt: Cbf3 = bf16(C) and OWbf = bf16(out_w), one kernel -------
__global__ void k_cvt2(const float* __restrict__ Cf, const float* __restrict__ OW,
                       __bf16* __restrict__ Cb3, __bf16* __restrict__ OWb) {
  const size_t NC = (size_t)NB * LC * DM;   // 8,388,608 elems (8192 blocks)
  size_t i = ((size_t)blockIdx.x * 256 + threadIdx.x) * 4;
  const float* src; __bf16* dst; size_t j;
  if (i < NC) { src = Cf; dst = Cb3; j = i; }
  else        { src = OW; dst = OWb; j = i - NC; }
  float4 f = *(const float4*)(src + j);
  v4bf h; h[0] = (__bf16)f.x; h[1] = (__bf16)f.y; h[2] = (__bf16)f.z; h[3] = (__bf16)f.w;
  *(v4bf*)(dst + j) = h;
}

// ---------------- G1: S = cw1 + qw2 + Cbf @ Qw3^T  (gload_lds) ----------------
__global__ __launch_bounds__(256) void k_mfma_S(
    const __bf16* __restrict__ Cbf, const __bf16* __restrict__ Qw3,
    const float* __restrict__ cw1, const float* __restrict__ qw2,
    float* __restrict__ S) {
  GEMM_PROLOG
  const __bf16* Arow = Cbf + (size_t)b * LC * DM + (size_t)(i0 + srow) * DM + scol;
  const __bf16* Brow = Qw3 + (size_t)b * LQ * DM + (size_t)(n0 + srow) * DM + scol;
  GEMM_KLOOP(Arow, Brow, DM, DM, DM)
  float* Sb = S + (size_t)b * LC * LQ;
#pragma unroll
  for (int x = 0; x < 4; ++x) {
    const int mB = i0 + wm * 64 + x * 16 + quad * 4;
    float cv[4];
#pragma unroll
    for (int r = 0; r < 4; ++r) cv[r] = cw1[b * LC + mB + r];
#pragma unroll
    for (int y = 0; y < 4; ++y) {
      const int j = n0 + wn * 64 + y * 16 + col;
      const float qv = qw2[b * LQ + j];
#pragma unroll
      for (int r = 0; r < 4; ++r)
        Sb[(size_t)(mB + r) * LQ + j] = acc[x][y][r] + cv[r] + qv;
    }
  }
}

// ---- fused: row softmax (qmask) -> S1  AND  per-64i-chunk column stats ----
__global__ __launch_bounds__(1024) void k_softstat(
    const float* __restrict__ S, const float* __restrict__ qmask,
    const float* __restrict__ cmask, __bf16* __restrict__ S1,
    float2* __restrict__ pstat) {
  __shared__ float2 cst[16][LQ];
  const int b = blockIdx.y, ic = blockIdx.x;
  const int tid = threadIdx.x, wv = tid >> 6, lane = tid & 63;
  const float* qm  = qmask + b * LQ;
  const float* cm  = cmask + b * LC + ic * 64;
  const float* Sb  = S  + ((size_t)b * LC + ic * 64) * LQ;
  __bf16*      S1b = S1 + ((size_t)b * LC + ic * 64) * LQ;
  float colm[8], cols[8];
#pragma unroll
  for (int tt = 0; tt < 8; ++tt) { colm[tt] = -3e38f; cols[tt] = 0.f; }
  for (int it = 0; it < 4; ++it) {
    const int r = wv * 4 + it;
    const float cmv = cm[r];
    const float* Srow = Sb + (size_t)r * LQ;
    float sv[8], l1[8];
    float m = -3e38f;
#pragma unroll
    for (int tt = 0; tt < 8; ++tt) {
      int j = lane + 64 * tt;
      sv[tt] = Srow[j];
      float qv = qm[j];
      l1[tt] = qv * sv[tt] + (1.f - qv) * NEGINF;
      m = fmaxf(m, l1[tt]);
    }
#pragma unroll
    for (int off = 32; off; off >>= 1) m = fmaxf(m, __shfl_xor(m, off, 64));
    float e[8], s = 0.f;
#pragma unroll
    for (int tt = 0; tt < 8; ++tt) { e[tt] = __expf(l1[tt] - m); s += e[tt]; }
#pragma unroll
    for (int off = 32; off; off >>= 1) s += __shfl_xor(s, off, 64);
    const float inv = 1.f / s;
#pragma unroll
    for (int tt = 0; tt < 8; ++tt)
      S1b[(size_t)r * LQ + lane + 64 * tt] = (__bf16)(e[tt] * inv);
#pragma unroll
    for (int tt = 0; tt < 8; ++tt) {
      float l2 = cmv * sv[tt] + (1.f - cmv) * NEGINF;
      if (l2 > colm[tt]) { cols[tt] *= __expf(colm[tt] - l2); colm[tt] = l2; }
      cols[tt] += __expf(l2 - colm[tt]);
    }
  }
#pragma unroll
  for (int tt = 0; tt < 8; ++tt) cst[wv][lane + 64 * tt] = make_float2(colm[tt], cols[tt]);
  __syncthreads();
  if (tid < LQ) {
    float M = -3e38f, Sd = 0.f;
#pragma unroll
    for (int k = 0; k < 16; ++k) {
      float2 p = cst[k][tid];
      float nM = fmaxf(M, p.x);
      Sd = Sd * __expf(M - nM) + p.y * __expf(p.x - nM);
      M = nM;
    }
    pstat[((size_t)(b * 16 + ic) * LQ) + tid] = make_float2(M, Sd);
  }
}

// ---- col softmax phase 2: combine chunk stats, write TRANSPOSED S2T[j][i] ----
__global__ void k_colwrite(const float* __restrict__ S, const float* __restrict__ cmask,
                           const float2* __restrict__ pstat, __bf16* __restrict__ S2T) {
  __shared__ float Mf[64], If[64];
  __shared__ __bf16 tile[64][66];
  const int b = blockIdx.z, ic = blockIdx.y, j0 = blockIdx.x * 64;
  const int c = threadIdx.x & 63, ip = threadIdx.x >> 6;
  if (threadIdx.x < 64) {
    float M = -3e38f, Sd = 0.f;
#pragma unroll
    for (int k = 0; k < 16; ++k) {
      float2 p = pstat[((size_t)(b * 16 + k) * LQ) + j0 + threadIdx.x];
      float nM = fmaxf(M, p.x);
      Sd = Sd * __expf(M - nM) + p.y * __expf(p.x - nM);
      M = nM;
    }
    Mf[threadIdx.x] = M; If[threadIdx.x] = 1.f / Sd;
  }
  __syncthreads();
  const float M = Mf[c], inv = If[c];
  const float* Sb = S + ((size_t)b * LC + ic * 64) * LQ;
  const float* cm = cmask + b * LC + ic * 64;
  for (int r = ip; r < 64; r += 4) {
    float mk = cm[r];
    float logit = mk * Sb[(size_t)r * LQ + j0 + c] + (1.f - mk) * NEGINF;
    tile[r][c] = (__bf16)(__expf(logit - M) * inv);
  }
  __syncthreads();
  __bf16* S2Tb = S2T + ((size_t)b * LQ + j0) * LC + ic * 64;
  for (int jr = ip; jr < 64; jr += 4)
    S2Tb[(size_t)jr * LC + c] = tile[c][jr];
}

// ---------------- G2: A = S1 @ Q; epilogue also emits CA = bf16(C*A) ---------
__global__ __launch_bounds__(256) void k_mfma_A(
    const __bf16* __restrict__ S1, const __bf16* __restrict__ QT,
    const float* __restrict__ Cf, __bf16* __restrict__ Aw, __bf16* __restrict__ CAw) {
  GEMM_PROLOG
  const __bf16* Arow = S1 + (size_t)b * LC * LQ + (size_t)(i0 + srow) * LQ + scol;
  const __bf16* Brow = QT + (size_t)b * DM * LQ + (size_t)(n0 + srow) * LQ + scol;
  GEMM_KLOOP(Arow, Brow, LQ, LQ, LQ)
  const float* Cb = Cf + (size_t)b * LC * DM;
  __bf16* Ab  = Aw  + (size_t)b * LC * DM;
  __bf16* CAb = CAw + (size_t)b * LC * DM;
#pragma unroll
  for (int x = 0; x < 4; ++x) {
    const int mB = i0 + wm * 64 + x * 16 + quad * 4;
#pragma unroll
    for (int y = 0; y < 4; ++y) {
      const int n = n0 + wn * 64 + y * 16 + col;
#pragma unroll
      for (int r = 0; r < 4; ++r) {
        const float av = acc[x][y][r];
        const float cv = Cb[(size_t)(mB + r) * DM + n];
        Ab[(size_t)(mB + r) * DM + n]  = (__bf16)av;
        CAb[(size_t)(mB + r) * DM + n] = (__bf16)(av * cv);
      }
    }
  }
}

// ------- G3: S2TC^T[n][j]  (A=S2T rows, B=CT rows; K=Lc; gload_lds) ----
__global__ __launch_bounds__(256) void k_mfma_T(
    const __bf16* __restrict__ S2T, const __bf16* __restrict__ CT, __bf16* __restrict__ S2TCT) {
  GEMM_PROLOG
  const int j0 = i0;
  const __bf16* Arow = S2T + (size_t)b * LQ * LC + (size_t)(j0 + srow) * LC + scol;
  const __bf16* Brow = CT  + (size_t)b * DM * LC + (size_t)(n0 + srow) * LC + scol;
  GEMM_KLOOP(Arow, Brow, LC, LC, LC)
#pragma unroll
  for (int x = 0; x < 4; ++x) {
    const int jB = j0 + wm * 64 + x * 16 + quad * 4;
#pragma unroll
    for (int y = 0; y < 4; ++y) {
      const int n = n0 + wn * 64 + y * 16 + col;
      v4bf h;
#pragma unroll
      for (int r = 0; r < 4; ++r) h[r] = (__bf16)acc[x][y][r];
      *(v4bf*)&S2TCT[((size_t)b * DM + n) * LQ + jB] = h;
    }
  }
}

// ---------- G4: Bm = S1 @ S2TC; epilogue emits CB = bf16(C*Bm) only ----------
__global__ __launch_bounds__(256) void k_mfma_Bm(
    const __bf16* __restrict__ S1, const __bf16* __restrict__ S2TCT,
    const float* __restrict__ Cf, __bf16* __restrict__ CBw) {
  GEMM_PROLOG
  const __bf16* Arow = S1    + (size_t)b * LC * LQ + (size_t)(i0 + srow) * LQ + scol;
  const __bf16* Brow = S2TCT + (size_t)b * DM * LQ + (size_t)(n0 + srow) * LQ + scol;
  GEMM_KLOOP(Arow, Brow, LQ, LQ, LQ)
  const float* Cb = Cf + (size_t)b * LC * DM;
  __bf16* CBb = CBw + (size_t)b * LC * DM;
#pragma unroll
  for (int x = 0; x < 4; ++x) {
    const int mB = i0 + wm * 64 + x * 16 + quad * 4;
#pragma unroll
    for (int y = 0; y < 4; ++y) {
      const int n = n0 + wn * 64 + y * 16 + col;
#pragma unroll
      for (int r = 0; r < 4; ++r) {
        const float cv = Cb[(size_t)(mB + r) * DM + n];
        CBb[(size_t)(mB + r) * DM + n] = (__bf16)(acc[x][y][r] * cv);
      }
    }
  }
}

// -------- G5: out = [Cbf|Aw|CAw|CBw] @ OW^T + out_b  (pure 4-seg GEMM) ------
__global__ __launch_bounds__(256) void k_mfma_out(
    const __bf16* __restrict__ Cb3, const __bf16* __restrict__ Aw,
    const __bf16* __restrict__ CAw, const __bf16* __restrict__ CBw,
    const __bf16* __restrict__ OWb, const float* __restrict__ ob,
    float* __restrict__ out) {
  GEMM_PROLOG
  const size_t rowoff = (size_t)b * LC * DM + (size_t)(i0 + srow) * DM + scol;
  const __bf16* As0 = Cb3 + rowoff;
  const __bf16* As1 = Aw  + rowoff;
  const __bf16* As2 = CAw + rowoff;
  const __bf16* As3 = CBw + rowoff;
  const __bf16* Brow0 = OWb + (size_t)(n0 + srow) * D4 + scol;
#pragma unroll
  for (int seg = 0; seg < 4; ++seg) {
    const __bf16* Arow = (seg == 0) ? As0 : (seg == 1) ? As1 : (seg == 2) ? As2 : As3;
    const __bf16* Brow = Brow0 + seg * DM;
    GEMM_KLOOP(Arow, Brow, DM, D4, DM)
  }
  float* outb = out + (size_t)b * LC * DM;
#pragma unroll
  for (int x = 0; x < 4; ++x) {
    const int mB = i0 + wm * 64 + x * 16 + quad * 4;
#pragma unroll
    for (int y = 0; y < 4; ++y) {
      const int n = n0 + wn * 64 + y * 16 + col;
      const float bv = ob[n];
#pragma unroll
      for (int r = 0; r < 4; ++r)
        outb[(size_t)(mB + r) * DM + n] = acc[x][y][r] + bv;
    }
  }
}

extern "C" void kernel_launch(void* const* d_in, const int* in_sizes, int n_in,
                              void* d_out, int out_size, void* d_ws, size_t ws_size,
                              hipStream_t stream) {
  const float* C     = (const float*)d_in[0];
  const float* Q     = (const float*)d_in[1];
  const float* cmask = (const float*)d_in[2];
  const float* qmask = (const float*)d_in[3];
  const float* w     = (const float*)d_in[4];
  const float* out_w = (const float*)d_in[5];
  const float* out_b = (const float*)d_in[6];
  float* out = (float*)d_out;

  // ---- workspace carve: 128 KiB header + 72 MiB region R, aliased by lifetime.
  // step:               1        2       3        4        5      6       7      8          9      10      11
  // [ 0,16):                     S----------------S  CT------CT          Aw----------------------------Aw
  // [16,32):                     S----------------S                QT------QT   CBw-----------------CBw   (CBw written step 9)
  // [32,48):  Cbf_e-----Cbf_e  S1-----------------------------------------S1          Cbf3--------Cbf3
  // [48,56):  Qw3---------Qw3
  // [48,64):                           S2T--------------S2T              CAw---------------------------CAw
  // [64,65):                    pstat--pstat
  // [64,72):                                            S2TCT---------------------S2TCT  OWbf[64,66)--OWbf
  char* base = (char*)d_ws;
  float*  cw1   = (float*)base;
  float*  qw2   = (float*)(base + 65536);
  char*   R     = base + 131072;
  float*  S     = (float*)R;                          // [0,32)   steps 2-4
  __bf16* CT    = (__bf16*)R;                         // [0,16)   steps 5-6
  __bf16* Aw    = (__bf16*)R;                         // [0,16)   steps 8-11
  __bf16* QT    = (__bf16*)(R + (16u << 20));         // [16,24)  steps 7-8
  __bf16* CBw   = (__bf16*)(R + (16u << 20));         // [16,32)  steps 9-11
  __bf16* Cbf_e = (__bf16*)(R + (32u << 20));         // [32,48)  steps 1-2
  __bf16* S1    = (__bf16*)(R + (32u << 20));         // [32,48)  steps 3-9
  __bf16* Cbf3  = (__bf16*)(R + (32u << 20));         // [32,48)  steps 10-11
  __bf16* Qw3   = (__bf16*)(R + (48u << 20));         // [48,56)  steps 1-2
  __bf16* S2T   = (__bf16*)(R + (48u << 20));         // [48,64)  steps 4-6
  __bf16* CAw   = (__bf16*)(R + (48u << 20));         // [48,64)  steps 8-11
  float2* pstat = (float2*)(R + (64u << 20));         // [64,65)  steps 3-4
  __bf16* S2TCT = (__bf16*)(R + (64u << 20));         // [64,72)  steps 6-9
  __bf16* OWbf  = (__bf16*)(R + (64u << 20));         // [64,66)  steps 10-11
  (void)in_sizes; (void)n_in; (void)out_size; (void)ws_size;

  // 1
  k_rowdots<<<(NB * LC + NB * LQ) / 4, 256, 0, stream>>>(C, Q, w, cw1, qw2, Cbf_e, Qw3);
  // 2
  k_mfma_S<<<dim3(LQ / 128, LC / 128, NB), 256, 0, stream>>>(Cbf_e, Qw3, cw1, qw2, S);
  // 3
  k_softstat<<<dim3(LC / 64, NB), 1024, 0, stream>>>(S, qmask, cmask, S1, pstat);
  // 4
  k_colwrite<<<dim3(LQ / 64, LC / 64, NB), 256, 0, stream>>>(S, cmask, pstat, S2T);
  // 5
  k_transpose<<<dim3(DM / 64, LC / 64, NB), 256, 0, stream>>>(C, CT, LC, DM);
  // 6
  k_mfma_T<<<dim3(DM / 128, LQ / 128, NB), 256, 0, stream>>>(S2T, CT, S2TCT);
  // 7
  k_transpose<<<dim3(DM / 64, LQ / 64, NB), 256, 0, stream>>>(Q, QT, LQ, DM);
  // 8
  k_mfma_A<<<dim3(DM / 128, LC / 128, NB), 256, 0, stream>>>(S1, QT, C, Aw, CAw);
  // 9
  k_mfma_Bm<<<dim3(DM / 128, LC / 128, NB), 256, 0, stream>>>(S1, S2TCT, C, CBw);
  // 10
  k_cvt2<<<(NB * LC * DM + DM * D4) / 1024, 256, 0, stream>>>(C, out_w, Cbf3, OWbf);
  // 11
  k_mfma_out<<<dim3(DM / 128, LC / 128, NB), 256, 0, stream>>>(Cbf3, Aw, CAw, CBw, OWbf, out_b, out);
}

// Round 3
// 279.788 us; speedup vs baseline: 1.0324x; 1.0324x over previous
//
#include <hip/hip_runtime.h>
#include <hip/hip_bf16.h>

// CQAttention: B=16, Lc=1024, Lq=512, d=512.  f32 I/O, bf16 MFMA GEMMs, f32 acc.
// Round 11: (1) all five GEMMs converted to the minimum-2-phase double-buffered
// schedule (T3-min+T4): stage(t+1) issued before compute(t), single
// inline-asm s_waitcnt vmcnt(0) + raw s_barrier per K-step -> stage latency
// hides under the MFMA phase.  k_mfma_out's 4 segments prefetch seamlessly
// across boundaries (unrolled seg loop, compile-time pointer select).
// (2) wave-uniform mask skips in k_softstat (cmask row skip of column stats)
// and k_colwrite (masked rows write 0 without S load / exp).

#define NB 16
#define LC 1024
#define LQ 512
#define DM 512
#define D4 2048
#define NEGINF (-1e30f)

typedef __bf16 v8bf __attribute__((ext_vector_type(8)));
typedef __bf16 v4bf __attribute__((ext_vector_type(4)));
typedef float  v4f  __attribute__((ext_vector_type(4)));

#define MFMA16 __builtin_amdgcn_mfma_f32_16x16x32_bf16

// direct global->LDS async copy, 16B per lane; LDS dest is wave-uniform base.
#define GLOAD16(gp, lp) __builtin_amdgcn_global_load_lds( \
    (const __attribute__((address_space(1))) void*)(gp), \
    (__attribute__((address_space(3))) void*)(lp), 16, 0, 0)

// ---- 4-wave gload_lds GEMM core: 128x128 tile, wave-tile 64x64, BK=64,
// ---- double-buffered LDS (64 KiB), min-2-phase counted schedule. ----
#define GEMM_PROLOG \
  __shared__ __bf16 Al[2][128 * 64], Bl[2][128 * 64]; \
  int bx = blockIdx.x, by = blockIdx.y, bz = blockIdx.z; \
  xcd_remap(bx, by, bz); \
  const int b = bz, i0 = by * 128, n0 = bx * 128; \
  const int t = threadIdx.x, lane = t & 63, wave = t >> 6; \
  const int wm = wave >> 1, wn = wave & 1, quad = lane >> 4, col = lane & 15; \
  const int srow = wave * 32 + (lane >> 3), scol = (lane & 7) * 8; \
  v4f acc[4][4]; \
  _Pragma("unroll") for (int x = 0; x < 4; ++x) \
  _Pragma("unroll") for (int y = 0; y < 4; ++y) \
  _Pragma("unroll") for (int r = 0; r < 4; ++r) acc[x][y][r] = 0.f;

#define GEMM_STAGE(buf, Aptr, Bptr, LDGA, LDGB, k0) \
  do { _Pragma("unroll") for (int u = 0; u < 4; ++u) { \
    GLOAD16((Aptr) + (size_t)(u * 8) * (LDGA) + (k0), &Al[buf][(wave * 32 + u * 8) * 64]); \
    GLOAD16((Bptr) + (size_t)(u * 8) * (LDGB) + (k0), &Bl[buf][(wave * 32 + u * 8) * 64]); \
  } } while (0)

#define GEMM_COMPUTE(buf) \
  do { _Pragma("unroll") for (int ko = 0; ko < 2; ++ko) { \
    v8bf af_[4], bf_[4]; \
    _Pragma("unroll") for (int x = 0; x < 4; ++x) \
      af_[x] = *(const v8bf*)&Al[buf][(wm * 64 + x * 16 + col) * 64 + ko * 32 + quad * 8]; \
    _Pragma("unroll") for (int y = 0; y < 4; ++y) \
      bf_[y] = *(const v8bf*)&Bl[buf][(wn * 64 + y * 16 + col) * 64 + ko * 32 + quad * 8]; \
    _Pragma("unroll") for (int x = 0; x < 4; ++x) \
    _Pragma("unroll") for (int y = 0; y < 4; ++y) \
      acc[x][y] = MFMA16(af_[x], bf_[y], acc[x][y], 0, 0, 0); \
  } } while (0)

// counted-wait + raw barrier; "memory" clobber fences LDS access reordering.
#define GEMM_SYNC() \
  do { asm volatile("s_waitcnt vmcnt(0)" ::: "memory"); \
       __builtin_amdgcn_s_barrier(); } while (0)

#define GEMM_KLOOP(Arow, Brow, LDGA, LDGB, KEXT) \
  { GEMM_STAGE(0, Arow, Brow, LDGA, LDGB, 0); \
    GEMM_SYNC(); \
    int cur_ = 0; \
    for (int k0 = 0; k0 < (KEXT); k0 += 64) { \
      const int kn_ = k0 + 64; \
      if (kn_ < (KEXT)) GEMM_STAGE(cur_ ^ 1, Arow, Brow, LDGA, LDGB, kn_); \
      GEMM_COMPUTE(cur_); \
      GEMM_SYNC(); \
      cur_ ^= 1; \
    } }

// XCD-aware remap (L2 locality for n-tile siblings sharing an A-tile).
__device__ __forceinline__ void xcd_remap(int& bx, int& by, int& bz) {
  const int gx = gridDim.x, gy = gridDim.y, gz = gridDim.z;
  int flat = bx + gx * (by + gy * bz);
  int per = (gx * gy * gz) >> 3;
  int nw = (flat & 7) * per + (flat >> 3);
  bx = nw % gx;
  int r = nw / gx;
  by = r % gy;
  bz = r / gy;
}

// -------- K1: cw1[b,i] = C.w1, qw2[b,j] = Q.w2; also emits Cbf_e = bf16(C)
// -------- and Qw3 = bf16(Q*w3) for the pure-bf16 k_mfma_S. ----
__global__ void k_rowdots(const float* __restrict__ C, const float* __restrict__ Q,
                          const float* __restrict__ w,
                          float* __restrict__ cw1, float* __restrict__ qw2,
                          __bf16* __restrict__ Cbf, __bf16* __restrict__ Qw3) {
  const int wid = threadIdx.x >> 6, lane = threadIdx.x & 63;
  const int row = blockIdx.x * 4 + wid;
  const bool isC = row < NB * LC;
  const int lr = isC ? row : row - NB * LC;
  const float* src = (isC ? C : Q) + (size_t)lr * DM;
  const float* wv  = isC ? w : (w + DM);
  const float* w3  = w + 2 * DM;
  __bf16* dst = (isC ? Cbf : Qw3) + (size_t)lr * DM;
  float v = 0.f;
#pragma unroll
  for (int s = 0; s < 2; ++s) {
    const int k = lane * 4 + s * 256;
    float4 f = *(const float4*)(src + k);
    float4 g = *(const float4*)(wv + k);
    v += f.x * g.x + f.y * g.y + f.z * g.z + f.w * g.w;
    v4bf h;
    if (isC) {
      h[0] = (__bf16)f.x; h[1] = (__bf16)f.y; h[2] = (__bf16)f.z; h[3] = (__bf16)f.w;
    } else {
      float4 s3 = *(const float4*)(w3 + k);
      h[0] = (__bf16)(f.x * s3.x); h[1] = (__bf16)(f.y * s3.y);
      h[2] = (__bf16)(f.z * s3.z); h[3] = (__bf16)(f.w * s3.w);
    }
    *(v4bf*)(dst + k) = h;
  }
#pragma unroll
  for (int off = 32; off; off >>= 1) v += __shfl_down(v, off, 64);
  if (lane == 0) {
    if (isC) cw1[row] = v;
    else     qw2[lr] = v;
  }
}

// ------- batched transpose: f32 in[R][Cd] -> bf16 outT[Cd][R] -------
__global__ void k_transpose(const float* __restrict__ in, __bf16* __restrict__ outT,
                            int R, int Cd) {
  __shared__ __bf16 tile[64][66];
  const int b = blockIdx.z;
  const int r0 = blockIdx.y * 64, c0 = blockIdx.x * 64;
  const int tr = threadIdx.x >> 6, tc = threadIdx.x & 63;
  const float* inb = in + (size_t)b * R * Cd;
  __bf16* outb = outT + (size_t)b * Cd * R;
  for (int r = tr; r < 64; r += 4)
    tile[r][tc] = (__bf16)inb[(size_t)(r0 + r) * Cd + c0 + tc];
  __syncthreads();
  for (int c = tr; c < 64; c += 4)
    outb[(size_t)(c0 + c) * R + r0 + tc] = tile[tc][c];
}

// ------- late cvt: Cbf3 = bf16(C) and OWbf = bf16(out_w), one kernel -------
__global__ void k_cvt2(const float* __restrict__ Cf, const float* __restrict__ OW,
                       __bf16* __restrict__ Cb3, __bf16* __restrict__ OWb) {
  const size_t NC = (size_t)NB * LC * DM;   // 8,388,608 elems (8192 blocks)
  size_t i = ((size_t)blockIdx.x * 256 + threadIdx.x) * 4;
  const float* src; __bf16* dst; size_t j;
  if (i < NC) { src = Cf; dst = Cb3; j = i; }
  else        { src = OW; dst = OWb; j = i - NC; }
  float4 f = *(const float4*)(src + j);
  v4bf h; h[0] = (__bf16)f.x; h[1] = (__bf16)f.y; h[2] = (__bf16)f.z; h[3] = (__bf16)f.w;
  *(v4bf*)(dst + j) = h;
}

// ---------------- G1: S = cw1 + qw2 + Cbf @ Qw3^T ----------------
__global__ __launch_bounds__(256) void k_mfma_S(
    const __bf16* __restrict__ Cbf, const __bf16* __restrict__ Qw3,
    const float* __restrict__ cw1, const float* __restrict__ qw2,
    float* __restrict__ S) {
  GEMM_PROLOG
  const __bf16* Arow = Cbf + (size_t)b * LC * DM + (size_t)(i0 + srow) * DM + scol;
  const __bf16* Brow = Qw3 + (size_t)b * LQ * DM + (size_t)(n0 + srow) * DM + scol;
  GEMM_KLOOP(Arow, Brow, DM, DM, DM)
  float* Sb = S + (size_t)b * LC * LQ;
#pragma unroll
  for (int x = 0; x < 4; ++x) {
    const int mB = i0 + wm * 64 + x * 16 + quad * 4;
    float cv[4];
#pragma unroll
    for (int r = 0; r < 4; ++r) cv[r] = cw1[b * LC + mB + r];
#pragma unroll
    for (int y = 0; y < 4; ++y) {
      const int j = n0 + wn * 64 + y * 16 + col;
      const float qv = qw2[b * LQ + j];
#pragma unroll
      for (int r = 0; r < 4; ++r)
        Sb[(size_t)(mB + r) * LQ + j] = acc[x][y][r] + cv[r] + qv;
    }
  }
}

// ---- fused: row softmax (qmask) -> S1  AND  per-64i-chunk column stats ----
__global__ __launch_bounds__(1024) void k_softstat(
    const float* __restrict__ S, const float* __restrict__ qmask,
    const float* __restrict__ cmask, __bf16* __restrict__ S1,
    float2* __restrict__ pstat) {
  __shared__ float2 cst[16][LQ];
  const int b = blockIdx.y, ic = blockIdx.x;
  const int tid = threadIdx.x, wv = tid >> 6, lane = tid & 63;
  const float* qm  = qmask + b * LQ;
  const float* cm  = cmask + b * LC + ic * 64;
  const float* Sb  = S  + ((size_t)b * LC + ic * 64) * LQ;
  __bf16*      S1b = S1 + ((size_t)b * LC + ic * 64) * LQ;
  float colm[8], cols[8];
#pragma unroll
  for (int tt = 0; tt < 8; ++tt) { colm[tt] = -3e38f; cols[tt] = 0.f; }
  for (int it = 0; it < 4; ++it) {
    const int r = wv * 4 + it;
    const float cmv = cm[r];
    const float* Srow = Sb + (size_t)r * LQ;
    float sv[8], l1[8];
    float m = -3e38f;
#pragma unroll
    for (int tt = 0; tt < 8; ++tt) {
      int j = lane + 64 * tt;
      sv[tt] = Srow[j];
      float qv = qm[j];
      l1[tt] = qv * sv[tt] + (1.f - qv) * NEGINF;
      m = fmaxf(m, l1[tt]);
    }
#pragma unroll
    for (int off = 32; off; off >>= 1) m = fmaxf(m, __shfl_xor(m, off, 64));
    float e[8], s = 0.f;
#pragma unroll
    for (int tt = 0; tt < 8; ++tt) { e[tt] = __expf(l1[tt] - m); s += e[tt]; }
#pragma unroll
    for (int off = 32; off; off >>= 1) s += __shfl_xor(s, off, 64);
    const float inv = 1.f / s;
#pragma unroll
    for (int tt = 0; tt < 8; ++tt)
      S1b[(size_t)r * LQ + lane + 64 * tt] = (__bf16)(e[tt] * inv);
    // column stats: cmv is 0/1 and wave-uniform -> skip masked rows entirely
    // (l2 = cmv ? sv : NEGINF; NEGINF contributes exactly 0 to chunk stats).
    if (cmv != 0.f) {
#pragma unroll
      for (int tt = 0; tt < 8; ++tt) {
        float l2 = sv[tt];
        if (l2 > colm[tt]) { cols[tt] *= __expf(colm[tt] - l2); colm[tt] = l2; }
        cols[tt] += __expf(l2 - colm[tt]);
      }
    }
  }
#pragma unroll
  for (int tt = 0; tt < 8; ++tt) cst[wv][lane + 64 * tt] = make_float2(colm[tt], cols[tt]);
  __syncthreads();
  if (tid < LQ) {
    float M = -3e38f, Sd = 0.f;
#pragma unroll
    for (int k = 0; k < 16; ++k) {
      float2 p = cst[k][tid];
      float nM = fmaxf(M, p.x);
      Sd = Sd * __expf(M - nM) + p.y * __expf(p.x - nM);
      M = nM;
    }
    pstat[((size_t)(b * 16 + ic) * LQ) + tid] = make_float2(M, Sd);
  }
}

// ---- col softmax phase 2: combine chunk stats, write TRANSPOSED S2T[j][i] ----
__global__ void k_colwrite(const float* __restrict__ S, const float* __restrict__ cmask,
                           const float2* __restrict__ pstat, __bf16* __restrict__ S2T) {
  __shared__ float Mf[64], If[64];
  __shared__ __bf16 tile[64][66];
  const int b = blockIdx.z, ic = blockIdx.y, j0 = blockIdx.x * 64;
  const int c = threadIdx.x & 63, ip = threadIdx.x >> 6;
  if (threadIdx.x < 64) {
    float M = -3e38f, Sd = 0.f;
#pragma unroll
    for (int k = 0; k < 16; ++k) {
      float2 p = pstat[((size_t)(b * 16 + k) * LQ) + j0 + threadIdx.x];
      float nM = fmaxf(M, p.x);
      Sd = Sd * __expf(M - nM) + p.y * __expf(p.x - nM);
      M = nM;
    }
    Mf[threadIdx.x] = M; If[threadIdx.x] = 1.f / Sd;
  }
  __syncthreads();
  const float M = Mf[c], inv = If[c];
  const float* Sb = S + ((size_t)b * LC + ic * 64) * LQ;
  const float* cm = cmask + b * LC + ic * 64;
  for (int r = ip; r < 64; r += 4) {
    // mk is 0/1 and wave-uniform per row: masked rows are exactly 0
    // (exp(NEGINF - M) == 0) -> skip the S load and the exp.
    if (cm[r] != 0.f)
      tile[r][c] = (__bf16)(__expf(Sb[(size_t)r * LQ + j0 + c] - M) * inv);
    else
      tile[r][c] = (__bf16)0.f;
  }
  __syncthreads();
  __bf16* S2Tb = S2T + ((size_t)b * LQ + j0) * LC + ic * 64;
  for (int jr = ip; jr < 64; jr += 4)
    S2Tb[(size_t)jr * LC + c] = tile[c][jr];
}

// ---------------- G2: A = S1 @ Q; epilogue also emits CA = bf16(C*A) ---------
__global__ __launch_bounds__(256) void k_mfma_A(
    const __bf16* __restrict__ S1, const __bf16* __restrict__ QT,
    const float* __restrict__ Cf, __bf16* __restrict__ Aw, __bf16* __restrict__ CAw) {
  GEMM_PROLOG
  const __bf16* Arow = S1 + (size_t)b * LC * LQ + (size_t)(i0 + srow) * LQ + scol;
  const __bf16* Brow = QT + (size_t)b * DM * LQ + (size_t)(n0 + srow) * LQ + scol;
  GEMM_KLOOP(Arow, Brow, LQ, LQ, LQ)
  const float* Cb = Cf + (size_t)b * LC * DM;
  __bf16* Ab  = Aw  + (size_t)b * LC * DM;
  __bf16* CAb = CAw + (size_t)b * LC * DM;
#pragma unroll
  for (int x = 0; x < 4; ++x) {
    const int mB = i0 + wm * 64 + x * 16 + quad * 4;
#pragma unroll
    for (int y = 0; y < 4; ++y) {
      const int n = n0 + wn * 64 + y * 16 + col;
#pragma unroll
      for (int r = 0; r < 4; ++r) {
        const float av = acc[x][y][r];
        const float cv = Cb[(size_t)(mB + r) * DM + n];
        Ab[(size_t)(mB + r) * DM + n]  = (__bf16)av;
        CAb[(size_t)(mB + r) * DM + n] = (__bf16)(av * cv);
      }
    }
  }
}

// ------- G3: S2TC^T[n][j]  (A=S2T rows, B=CT rows; K=Lc) ----
__global__ __launch_bounds__(256) void k_mfma_T(
    const __bf16* __restrict__ S2T, const __bf16* __restrict__ CT, __bf16* __restrict__ S2TCT) {
  GEMM_PROLOG
  const int j0 = i0;
  const __bf16* Arow = S2T + (size_t)b * LQ * LC + (size_t)(j0 + srow) * LC + scol;
  const __bf16* Brow = CT  + (size_t)b * DM * LC + (size_t)(n0 + srow) * LC + scol;
  GEMM_KLOOP(Arow, Brow, LC, LC, LC)
#pragma unroll
  for (int x = 0; x < 4; ++x) {
    const int jB = j0 + wm * 64 + x * 16 + quad * 4;
#pragma unroll
    for (int y = 0; y < 4; ++y) {
      const int n = n0 + wn * 64 + y * 16 + col;
      v4bf h;
#pragma unroll
      for (int r = 0; r < 4; ++r) h[r] = (__bf16)acc[x][y][r];
      *(v4bf*)&S2TCT[((size_t)b * DM + n) * LQ + jB] = h;
    }
  }
}

// ---------- G4: Bm = S1 @ S2TC; epilogue emits CB = bf16(C*Bm) only ----------
__global__ __launch_bounds__(256) void k_mfma_Bm(
    const __bf16* __restrict__ S1, const __bf16* __restrict__ S2TCT,
    const float* __restrict__ Cf, __bf16* __restrict__ CBw) {
  GEMM_PROLOG
  const __bf16* Arow = S1    + (size_t)b * LC * LQ + (size_t)(i0 + srow) * LQ + scol;
  const __bf16* Brow = S2TCT + (size_t)b * DM * LQ + (size_t)(n0 + srow) * LQ + scol;
  GEMM_KLOOP(Arow, Brow, LQ, LQ, LQ)
  const float* Cb = Cf + (size_t)b * LC * DM;
  __bf16* CBb = CBw + (size_t)b * LC * DM;
#pragma unroll
  for (int x = 0; x < 4; ++x) {
    const int mB = i0 + wm * 64 + x * 16 + quad * 4;
#pragma unroll
    for (int y = 0; y < 4; ++y) {
      const int n = n0 + wn * 64 + y * 16 + col;
#pragma unroll
      for (int r = 0; r < 4; ++r) {
        const float cv = Cb[(size_t)(mB + r) * DM + n];
        CBb[(size_t)(mB + r) * DM + n] = (__bf16)(acc[x][y][r] * cv);
      }
    }
  }
}

// -------- G5: out = [Cbf|Aw|CAw|CBw] @ OW^T + out_b  (pure 4-seg GEMM,
// -------- seamless cross-segment prefetch) ------
__global__ __launch_bounds__(256) void k_mfma_out(
    const __bf16* __restrict__ Cb3, const __bf16* __restrict__ Aw,
    const __bf16* __restrict__ CAw, const __bf16* __restrict__ CBw,
    const __bf16* __restrict__ OWb, const float* __restrict__ ob,
    float* __restrict__ out) {
  GEMM_PROLOG
  const size_t rowoff = (size_t)b * LC * DM + (size_t)(i0 + srow) * DM + scol;
  const __bf16* As0 = Cb3 + rowoff;
  const __bf16* As1 = Aw  + rowoff;
  const __bf16* As2 = CAw + rowoff;
  const __bf16* As3 = CBw + rowoff;
  const __bf16* Brow0 = OWb + (size_t)(n0 + srow) * D4 + scol;
  GEMM_STAGE(0, As0, Brow0, DM, D4, 0);
  GEMM_SYNC();
  int cur_ = 0;
#pragma unroll
  for (int seg = 0; seg < 4; ++seg) {
    const __bf16* Arow  = (seg == 0) ? As0 : (seg == 1) ? As1 : (seg == 2) ? As2 : As3;
    const __bf16* Anext = (seg == 0) ? As1 : (seg == 1) ? As2 : As3;
    const __bf16* Brow  = Brow0 + seg * DM;
    const __bf16* Bnext = Brow0 + (seg < 3 ? seg + 1 : 3) * DM;
    for (int k0 = 0; k0 < DM; k0 += 64) {
      const int kn_ = k0 + 64;
      if (kn_ < DM)      GEMM_STAGE(cur_ ^ 1, Arow, Brow, DM, D4, kn_);
      else if (seg < 3)  GEMM_STAGE(cur_ ^ 1, Anext, Bnext, DM, D4, 0);
      GEMM_COMPUTE(cur_);
      GEMM_SYNC();
      cur_ ^= 1;
    }
  }
  float* outb = out + (size_t)b * LC * DM;
#pragma unroll
  for (int x = 0; x < 4; ++x) {
    const int mB = i0 + wm * 64 + x * 16 + quad * 4;
#pragma unroll
    for (int y = 0; y < 4; ++y) {
      const int n = n0 + wn * 64 + y * 16 + col;
      const float bv = ob[n];
#pragma unroll
      for (int r = 0; r < 4; ++r)
        outb[(size_t)(mB + r) * DM + n] = acc[x][y][r] + bv;
    }
  }
}

extern "C" void kernel_launch(void* const* d_in, const int* in_sizes, int n_in,
                              void* d_out, int out_size, void* d_ws, size_t ws_size,
                              hipStream_t stream) {
  const float* C     = (const float*)d_in[0];
  const float* Q     = (const float*)d_in[1];
  const float* cmask = (const float*)d_in[2];
  const float* qmask = (const float*)d_in[3];
  const float* w     = (const float*)d_in[4];
  const float* out_w = (const float*)d_in[5];
  const float* out_b = (const float*)d_in[6];
  float* out = (float*)d_out;

  // ---- workspace carve: 128 KiB header + 72 MiB region R, aliased by lifetime.
  // step:               1        2       3        4        5      6       7      8          9      10      11
  // [ 0,16):                     S----------------S  CT------CT          Aw----------------------------Aw
  // [16,32):                     S----------------S                QT------QT   CBw-----------------CBw
  // [32,48):  Cbf_e-----Cbf_e  S1-----------------------------------------S1          Cbf3--------Cbf3
  // [48,56):  Qw3---------Qw3
  // [48,64):                           S2T--------------S2T              CAw---------------------------CAw
  // [64,65):                    pstat--pstat
  // [64,72):                                            S2TCT---------------------S2TCT  OWbf[64,66)--OWbf
  char* base = (char*)d_ws;
  float*  cw1   = (float*)base;
  float*  qw2   = (float*)(base + 65536);
  char*   R     = base + 131072;
  float*  S     = (float*)R;                          // [0,32)   steps 2-4
  __bf16* CT    = (__bf16*)R;                         // [0,16)   steps 5-6
  __bf16* Aw    = (__bf16*)R;                         // [0,16)   steps 8-11
  __bf16* QT    = (__bf16*)(R + (16u << 20));         // [16,24)  steps 7-8
  __bf16* CBw   = (__bf16*)(R + (16u << 20));         // [16,32)  steps 9-11
  __bf16* Cbf_e = (__bf16*)(R + (32u << 20));         // [32,48)  steps 1-2
  __bf16* S1    = (__bf16*)(R + (32u << 20));         // [32,48)  steps 3-9
  __bf16* Cbf3  = (__bf16*)(R + (32u << 20));         // [32,48)  steps 10-11
  __bf16* Qw3   = (__bf16*)(R + (48u << 20));         // [48,56)  steps 1-2
  __bf16* S2T   = (__bf16*)(R + (48u << 20));         // [48,64)  steps 4-6
  __bf16* CAw   = (__bf16*)(R + (48u << 20));         // [48,64)  steps 8-11
  float2* pstat = (float2*)(R + (64u << 20));         // [64,65)  steps 3-4
  __bf16* S2TCT = (__bf16*)(R + (64u << 20));         // [64,72)  steps 6-9
  __bf16* OWbf  = (__bf16*)(R + (64u << 20));         // [64,66)  steps 10-11
  (void)in_sizes; (void)n_in; (void)out_size; (void)ws_size;

  // 1
  k_rowdots<<<(NB * LC + NB * LQ) / 4, 256, 0, stream>>>(C, Q, w, cw1, qw2, Cbf_e, Qw3);
  // 2
  k_mfma_S<<<dim3(LQ / 128, LC / 128, NB), 256, 0, stream>>>(Cbf_e, Qw3, cw1, qw2, S);
  // 3
  k_softstat<<<dim3(LC / 64, NB), 1024, 0, stream>>>(S, qmask, cmask, S1, pstat);
  // 4
  k_colwrite<<<dim3(LQ / 64, LC / 64, NB), 256, 0, stream>>>(S, cmask, pstat, S2T);
  // 5
  k_transpose<<<dim3(DM / 64, LC / 64, NB), 256, 0, stream>>>(C, CT, LC, DM);
  // 6
  k_mfma_T<<<dim3(DM / 128, LQ / 128, NB), 256, 0, stream>>>(S2T, CT, S2TCT);
  // 7
  k_transpose<<<dim3(DM / 64, LQ / 64, NB), 256, 0, stream>>>(Q, QT, LQ, DM);
  // 8
  k_mfma_A<<<dim3(DM / 128, LC / 128, NB), 256, 0, stream>>>(S1, QT, C, Aw, CAw);
  // 9
  k_mfma_Bm<<<dim3(DM / 128, LC / 128, NB), 256, 0, stream>>>(S1, S2TCT, C, CBw);
  // 10
  k_cvt2<<<(NB * LC * DM + DM * D4) / 1024, 256, 0, stream>>>(C, out_w, Cbf3, OWbf);
  // 11
  k_mfma_out<<<dim3(DM / 128, LC / 128, NB), 256, 0, stream>>>(Cbf3, Aw, CAw, CBw, OWbf, out_b, out);
}